// Round 8
// baseline (104.801 us; speedup 1.0000x reference)
//
#include <hip/hip_runtime.h>

// N = 8192 rows, D = 512 features.
// loss = mean((1-cos)^2) over all pairs (margin=1 makes labels irrelevant:
//        max(1-cos,0)^2 == (1-cos)^2 since cos <= 1).
// N^2*loss = N^2 - 2*||s||^2 + ||Xn^T Xn||_F^2,  s_a = sum_i xn[i][a].
// G = Xn^T Xn is 512x512 symmetric -> 136 upper-triangle 32x32 tiles,
// off-diagonal tiles weighted 2 in the Frobenius sum.
//
// xt is FRAGMENT-MAJOR: 1 KiB block per (g = feature-group of 16,
// c = sample-chunk of 32); lane l holds 16 B for (feature-row = l&15,
// k-slice = l>>4), elem e = sample c*32 + (l>>4)*8 + e — exactly the
// mfma_f32_16x16x32_bf16 A/B fragment. Gram loads = contiguous 1 KiB/wave.

typedef __attribute__((ext_vector_type(8))) short  s8;      // 8 bf16 payload
typedef __attribute__((ext_vector_type(8))) __bf16 bf8;     // mfma operand
typedef __attribute__((ext_vector_type(4))) float  f4;

#define NT32 136                 // 16*17/2 upper-triangle 32x32 tiles
#define KOUT 16                  // K splits
#define KCW  512                 // 8192 / KOUT (= 16 kchunks of 32)
#define GSTRIDE (256 * 512)      // ushorts per g-group (256 chunks * 512)
#define PLANE_F4 (NT32 * 256)    // f4 cells per partial plane
#define RBLK 272                 // gp-reduce blocks (34816 cells / 128)
#define SBLK 32                  // svec blocks (one per g)

// ws layout (bytes)
#define OFF_XT  0u                               // bf16 xt[32g][256c][64l][8] = 8 MiB
#define OFF_S2  (8u * 1024u * 1024u)             // f32 s2[1]
#define OFF_TK  (OFF_S2 + 4u)                    // int ticket[1]
#define OFF_GP  (OFF_S2 + 64u)                   // f32 gp[KOUT][NT32][1024] = 8.9 MiB

__device__ __forceinline__ unsigned short f2bf(float f) {
    union { float f; unsigned u; } v; v.f = f;
    unsigned r = v.u + 0x7FFFu + ((v.u >> 16) & 1u);   // RNE
    return (unsigned short)(r >> 16);
}
__device__ __forceinline__ float bf2f(unsigned short h) {
    union { unsigned u; float f; } v; v.u = ((unsigned)h) << 16;
    return v.f;
}

// --- K1: fused norms + normalize + fragment-major transpose.
//     Block b (1024 total) owns 8 rows: chunk c = b>>2, k-slice ks = b&3. ---
__global__ __launch_bounds__(256) void k_prep(
    const float* __restrict__ reps, unsigned short* __restrict__ xt,
    float* __restrict__ s2, int* __restrict__ ticket)
{
    __shared__ unsigned short tile[8][528];     // 512 + 16 pad
    const int t = threadIdx.x;
    const int b = blockIdx.x;
    if (b == 0 && t == 0) { *s2 = 0.f; *ticket = 0; }
    const int c = b >> 2, ks = b & 3;
    const int j = t >> 5;                       // local row 0..7
    const int cl = t & 31;                      // 32 threads per row

    const float* rp = reps + (size_t)(c * 32 + ks * 8 + j) * 512 + cl * 4;
    float4 v[4];
    float ss = 0.f;
    #pragma unroll
    for (int q = 0; q < 4; ++q) {
        v[q] = *(const float4*)(rp + q * 128);
        ss += v[q].x*v[q].x + v[q].y*v[q].y + v[q].z*v[q].z + v[q].w*v[q].w;
    }
    ss += __shfl_xor(ss, 1, 64);  ss += __shfl_xor(ss, 2, 64);
    ss += __shfl_xor(ss, 4, 64);  ss += __shfl_xor(ss, 8, 64);
    ss += __shfl_xor(ss, 16, 64);               // sum over the 32-lane row group
    const float inv = 1.0f / fmaxf(sqrtf(ss), 1e-8f);
    #pragma unroll
    for (int q = 0; q < 4; ++q) {
        ushort4 p;
        p.x = f2bf(v[q].x * inv); p.y = f2bf(v[q].y * inv);
        p.z = f2bf(v[q].z * inv); p.w = f2bf(v[q].w * inv);
        *(ushort4*)&tile[j][cl * 4 + q * 128] = p;
    }
    __syncthreads();

    // write 2 fragment slots per thread; slot s: feature a = s, g = s>>4, rl = s&15
    #pragma unroll
    for (int s_ = 0; s_ < 2; ++s_) {
        const int a = t + s_ * 256;
        const int g = a >> 4, rl = a & 15;
        ushort4 o0, o1;
        o0.x = tile[0][a]; o0.y = tile[1][a]; o0.z = tile[2][a]; o0.w = tile[3][a];
        o1.x = tile[4][a]; o1.y = tile[5][a]; o1.z = tile[6][a]; o1.w = tile[7][a];
        unsigned short* dst = xt + ((size_t)g << 17) + ((size_t)c << 9)
                                 + (ks * 16 + rl) * 8;
        *(ushort4*)(dst)     = o0;
        *(ushort4*)(dst + 4) = o1;
    }
}

// --- K2: partial Gram, 32x32 upper-tri tiles; 1 wave = 1 tile x K-chunk.
//     Fragment-major xt: each operand load = contiguous 1 KiB per wave.
//     (byte-identical to round 6/7 — proven) ---
__global__ __launch_bounds__(64) void k_gram(
    const unsigned short* __restrict__ xt, float* __restrict__ gp)
{
    const int lane = threadIdx.x;
    const int l15 = lane & 15, l4 = lane >> 4;
    int tt = blockIdx.x, ta = 0;
    while (tt >= 16 - ta) { tt -= 16 - ta; ++ta; }
    const int tb = ta + tt;
    const int c0 = blockIdx.y * (KCW / 32);      // 16 kchunks per block
    const unsigned short* A0 = xt + (((size_t)(ta * 2) * 256 + c0) << 9) + lane * 8;
    const unsigned short* B0 = xt + (((size_t)(tb * 2) * 256 + c0) << 9) + lane * 8;

    f4 acc00 = {0.f,0.f,0.f,0.f}, acc01 = {0.f,0.f,0.f,0.f};
    f4 acc10 = {0.f,0.f,0.f,0.f}, acc11 = {0.f,0.f,0.f,0.f};

    if (ta != tb) {
        for (int cc = 0; cc < 16; ++cc) {
            const s8 av0 = *(const s8*)(A0 + cc * 512);
            const s8 av1 = *(const s8*)(A0 + GSTRIDE + cc * 512);
            const s8 bv0 = *(const s8*)(B0 + cc * 512);
            const s8 bv1 = *(const s8*)(B0 + GSTRIDE + cc * 512);
            acc00 = __builtin_amdgcn_mfma_f32_16x16x32_bf16(
                __builtin_bit_cast(bf8, av0), __builtin_bit_cast(bf8, bv0), acc00, 0, 0, 0);
            acc01 = __builtin_amdgcn_mfma_f32_16x16x32_bf16(
                __builtin_bit_cast(bf8, av0), __builtin_bit_cast(bf8, bv1), acc01, 0, 0, 0);
            acc10 = __builtin_amdgcn_mfma_f32_16x16x32_bf16(
                __builtin_bit_cast(bf8, av1), __builtin_bit_cast(bf8, bv0), acc10, 0, 0, 0);
            acc11 = __builtin_amdgcn_mfma_f32_16x16x32_bf16(
                __builtin_bit_cast(bf8, av1), __builtin_bit_cast(bf8, bv1), acc11, 0, 0, 0);
        }
    } else {
        for (int cc = 0; cc < 16; ++cc) {
            const s8 av0 = *(const s8*)(A0 + cc * 512);
            const s8 av1 = *(const s8*)(A0 + GSTRIDE + cc * 512);
            acc00 = __builtin_amdgcn_mfma_f32_16x16x32_bf16(
                __builtin_bit_cast(bf8, av0), __builtin_bit_cast(bf8, av0), acc00, 0, 0, 0);
            acc01 = __builtin_amdgcn_mfma_f32_16x16x32_bf16(
                __builtin_bit_cast(bf8, av0), __builtin_bit_cast(bf8, av1), acc01, 0, 0, 0);
            acc10 = __builtin_amdgcn_mfma_f32_16x16x32_bf16(
                __builtin_bit_cast(bf8, av1), __builtin_bit_cast(bf8, av0), acc10, 0, 0, 0);
            acc11 = __builtin_amdgcn_mfma_f32_16x16x32_bf16(
                __builtin_bit_cast(bf8, av1), __builtin_bit_cast(bf8, av1), acc11, 0, 0, 0);
        }
    }

    float* gb = gp + ((size_t)blockIdx.y * NT32 + blockIdx.x) * 1024;
    #pragma unroll
    for (int r = 0; r < 4; ++r) {
        const int ar0 = (l4 * 4 + r) * 32 + l15;     // C/D: row=(l>>4)*4+r, col=l&15
        gb[ar0]           = acc00[r];
        gb[ar0 + 16]      = acc01[r];
        gb[ar0 + 16 * 32] = acc10[r];
        gb[ar0 + 16 * 33] = acc11[r];
    }
}

// --- K3 (304 blocks): blocks 0..271 -> s2 += wgt*(sum_K gp)^2 (plane-split);
//     blocks 272..303 -> s2 += -2*s_a^2 via column-sums of xt (one g each);
//     last-ticket block writes loss = (N^2 + s2)/N^2. ---
__global__ __launch_bounds__(256) void k_reduce_final(
    const float* __restrict__ gp, const unsigned short* __restrict__ xt,
    float* __restrict__ s2, int* __restrict__ ticket, float* __restrict__ out)
{
    __shared__ f4 sh[128];
    __shared__ float pw[4];
    __shared__ int lastFlag;
    const int t = threadIdx.x, lane = t & 63, wv = t >> 6;
    const int bx = blockIdx.x;

    if (bx < RBLK) {
        // gp Frobenius part: 128 cells/block, 2 threads per cell (8 planes each)
        const int cl = bx * 128 + (t & 127);
        const int h = t >> 7;
        const f4* g4 = (const f4*)gp;
        f4 s = {0.f, 0.f, 0.f, 0.f};
        #pragma unroll
        for (int p = 0; p < 8; ++p) s += g4[(size_t)(h * 8 + p) * PLANE_F4 + cl];
        if (h) sh[t & 127] = s;
        __syncthreads();
        float sq = 0.f;
        if (!h) {
            const f4 tot = s + sh[t];
            int tt = cl >> 8, ta = 0;                // 256 f4 per tile plane
            while (tt >= 16 - ta) { tt -= 16 - ta; ++ta; }
            const float wgt = (tt == 0) ? 1.f : 2.f; // diag vs off-diag tile
            sq = wgt * (tot.x*tot.x + tot.y*tot.y + tot.z*tot.z + tot.w*tot.w);
            #pragma unroll
            for (int off = 1; off < 64; off <<= 1) sq += __shfl_xor(sq, off, 64);
        }
        if (!h && lane == 0) pw[wv] = sq;            // waves 0,1 only
        __syncthreads();
        if (t == 0) {
            atomicAdd(s2, pw[0] + pw[1]);
            __threadfence();
            lastFlag = (atomicAdd(ticket, 1) == (int)gridDim.x - 1);
        }
    } else {
        // svec part: block owns g; lane sums its 8 bf16 across 64 chunks/wave
        const int g = bx - RBLK;
        const unsigned short* base = xt + ((size_t)g << 17) + lane * 8;
        float acc = 0.f;
        for (int c = wv * 64; c < wv * 64 + 64; ++c) {
            const ushort4 u0 = *(const ushort4*)(base + ((size_t)c << 9));
            const ushort4 u1 = *(const ushort4*)(base + ((size_t)c << 9) + 4);
            acc += bf2f(u0.x) + bf2f(u0.y) + bf2f(u0.z) + bf2f(u0.w)
                 + bf2f(u1.x) + bf2f(u1.y) + bf2f(u1.z) + bf2f(u1.w);
        }
        acc += __shfl_xor(acc, 16, 64);
        acc += __shfl_xor(acc, 32, 64);              // lanes 0-15: per-feature sums
        if (lane < 16) ((float*)sh)[wv * 16 + lane] = acc;
        __syncthreads();
        if (t < 16) {
            const float* svp = (const float*)sh;
            const float sa = svp[t] + svp[16 + t] + svp[32 + t] + svp[48 + t];
            float q = sa * sa;
            q += __shfl_xor(q, 1, 64); q += __shfl_xor(q, 2, 64);
            q += __shfl_xor(q, 4, 64); q += __shfl_xor(q, 8, 64);
            if (t == 0) {
                atomicAdd(s2, -2.f * q);
                __threadfence();
                lastFlag = (atomicAdd(ticket, 1) == (int)gridDim.x - 1);
            }
        }
    }
    __syncthreads();
    if (lastFlag && t == 0) {                        // any block can be last
        __threadfence();
        const float S = atomicAdd(s2, 0.f);          // S2 - 2*s1, complete
        const double NN = 67108864.0;                // 8192^2
        out[0] = (float)((NN + (double)S) / NN);
    }
}

extern "C" void kernel_launch(void* const* d_in, const int* in_sizes, int n_in,
                              void* d_out, int out_size, void* d_ws, size_t ws_size,
                              hipStream_t stream)
{
    const float* reps = (const float*)d_in[0];
    // d_in[1] (labels) is mathematically irrelevant for margin = 1.0.
    char* ws = (char*)d_ws;
    unsigned short* xt   = (unsigned short*)(ws + OFF_XT);
    float*          s2   = (float*)(ws + OFF_S2);
    int*            tick = (int*)(ws + OFF_TK);
    float*          gp   = (float*)(ws + OFF_GP);

    k_prep<<<1024, 256, 0, stream>>>(reps, xt, s2, tick);
    k_gram<<<dim3(NT32, KOUT), 64, 0, stream>>>(xt, gp);
    k_reduce_final<<<RBLK + SBLK, 256, 0, stream>>>(gp, xt, s2, tick, (float*)d_out);
}

// Round 9
// 87.517 us; speedup vs baseline: 1.1975x; 1.1975x over previous
//
#include <hip/hip_runtime.h>

// N = 8192 rows, D = 512 features.
// loss = mean((1-cos)^2) over all pairs (margin=1 makes labels irrelevant:
//        max(1-cos,0)^2 == (1-cos)^2 since cos <= 1).
// N^2*loss = N^2 - 2*||s||^2 + ||Xn^T Xn||_F^2,  s_a = sum_i xn[i][a].
// G = Xn^T Xn is 512x512 symmetric -> 136 upper-triangle 32x32 tiles,
// off-diagonal tiles weighted 2 in the Frobenius sum.
//
// xt is FRAGMENT-MAJOR: 1 KiB block per (g = feature-group of 16,
// c = sample-chunk of 32); lane l holds 16 B for (feature-row = l&15,
// k-slice = l>>4) — exactly the mfma_f32_16x16x32_bf16 A/B fragment.
// Gram loads are contiguous 1 KiB per wave (zero overfetch).
//
// This is the round-7 (87.3 us) source with ONE change: #pragma unroll on
// k_gram's cc loops (deepen load pipelining under MFMA).

typedef __attribute__((ext_vector_type(8))) short  s8;      // 8 bf16 payload
typedef __attribute__((ext_vector_type(8))) __bf16 bf8;     // mfma operand
typedef __attribute__((ext_vector_type(4))) float  f4;

#define NT32 136                 // 16*17/2 upper-triangle 32x32 tiles
#define KOUT 16                  // K splits
#define KCW  512                 // 8192 / KOUT (= 16 kchunks of 32)
#define GSTRIDE (256 * 512)      // ushorts per g-group (256 chunks * 512)

// ws layout (bytes)
#define OFF_XT  0u                               // bf16 xt[32g][256c][64l][8] = 8 MiB
#define OFF_S2  (8u * 1024u * 1024u)             // f32 s2[1]
#define OFF_TK  (OFF_S2 + 4u)                    // int ticket[1]
#define OFF_PRT (OFF_S2 + 64u)                   // f32 parts[256][512] = 512 KiB
#define OFF_GP  (OFF_PRT + 256u * 512u * 4u)     // f32 gp[KOUT][NT32][1024] = 8.9 MiB

__device__ __forceinline__ unsigned short f2bf(float f) {
    union { float f; unsigned u; } v; v.f = f;
    unsigned r = v.u + 0x7FFFu + ((v.u >> 16) & 1u);   // RNE
    return (unsigned short)(r >> 16);
}
__device__ __forceinline__ float bf2f(unsigned short h) {
    union { unsigned u; float f; } v; v.u = ((unsigned)h) << 16;
    return v.f;
}

// --- K1: fused norms + normalize + fragment-major transpose + svec parts.
//     Block b owns rows [32b, 32b+32) = sample-chunk c = b. 256 thr. ---
__global__ __launch_bounds__(256) void k_prep(
    const float* __restrict__ reps, unsigned short* __restrict__ xt,
    float* __restrict__ parts, float* __restrict__ s2, int* __restrict__ ticket)
{
    __shared__ unsigned short tile[32][528];    // 512 + 16 pad ushorts
    const int t = threadIdx.x, lane = t & 63, wv = t >> 6;
    const int b = blockIdx.x;
    if (b == 0 && t == 0) { *s2 = 0.f; *ticket = 0; }

    // phase A: load 32 rows, octet-reduce sumsq, normalize, pack to LDS
    const int row = wv * 8 + (lane >> 3);       // local row 0..31
    const int co  = (lane & 7) * 4;             // col base (f32)
    const float* rp = reps + (size_t)(b * 32 + row) * 512 + co;
    float4 v[16];
    float ss = 0.f;
    #pragma unroll
    for (int q = 0; q < 16; ++q) {
        v[q] = *(const float4*)(rp + 32 * q);
        ss += v[q].x*v[q].x + v[q].y*v[q].y + v[q].z*v[q].z + v[q].w*v[q].w;
    }
    ss += __shfl_xor(ss, 1, 64);
    ss += __shfl_xor(ss, 2, 64);
    ss += __shfl_xor(ss, 4, 64);                // all 8 octet lanes have row sumsq
    const float inv = 1.0f / fmaxf(sqrtf(ss), 1e-8f);
    #pragma unroll
    for (int q = 0; q < 16; ++q) {
        ushort4 p;
        p.x = f2bf(v[q].x * inv); p.y = f2bf(v[q].y * inv);
        p.z = f2bf(v[q].z * inv); p.w = f2bf(v[q].w * inv);
        *(ushort4*)&tile[row][co + 32 * q] = p;
    }
    __syncthreads();

    // phase B: fragment-major output. Slot (g, l): l = ks*16+rl holds
    // bf16 xn[b*32 + ks*8 + j][g*16 + rl], j=0..7.
    {
        const int rl = lane & 15, ks = lane >> 4;
        #pragma unroll
        for (int gg = 0; gg < 8; ++gg) {
            const int g = wv * 8 + gg;
            const int a = g * 16 + rl;
            ushort4 o0, o1;
            o0.x = tile[ks*8+0][a]; o0.y = tile[ks*8+1][a];
            o0.z = tile[ks*8+2][a]; o0.w = tile[ks*8+3][a];
            o1.x = tile[ks*8+4][a]; o1.y = tile[ks*8+5][a];
            o1.z = tile[ks*8+6][a]; o1.w = tile[ks*8+7][a];
            unsigned short* dst = xt + ((size_t)g << 17) + ((size_t)b << 9) + lane * 8;
            *(ushort4*)(dst)     = o0;
            *(ushort4*)(dst + 4) = o1;
        }
    }

    // phase C: svec partials for this 32-row chunk (features t and t+256)
    {
        float sA = 0.f, sB = 0.f;
        #pragma unroll
        for (int r = 0; r < 32; ++r) {
            sA += bf2f(tile[r][t]);
            sB += bf2f(tile[r][t + 256]);
        }
        parts[(size_t)b * 512 + t]       = sA;
        parts[(size_t)b * 512 + t + 256] = sB;
    }
}

// --- K2: partial Gram, 32x32 upper-tri tiles; 1 wave = 1 tile x K-chunk.
//     Fragment-major xt: each operand load = contiguous 1 KiB per wave. ---
__global__ __launch_bounds__(64) void k_gram(
    const unsigned short* __restrict__ xt, float* __restrict__ gp)
{
    const int lane = threadIdx.x;
    const int l15 = lane & 15, l4 = lane >> 4;
    int tt = blockIdx.x, ta = 0;
    while (tt >= 16 - ta) { tt -= 16 - ta; ++ta; }
    const int tb = ta + tt;
    const int c0 = blockIdx.y * (KCW / 32);      // 16 kchunks per block
    const unsigned short* A0 = xt + (((size_t)(ta * 2) * 256 + c0) << 9) + lane * 8;
    const unsigned short* B0 = xt + (((size_t)(tb * 2) * 256 + c0) << 9) + lane * 8;

    f4 acc00 = {0.f,0.f,0.f,0.f}, acc01 = {0.f,0.f,0.f,0.f};
    f4 acc10 = {0.f,0.f,0.f,0.f}, acc11 = {0.f,0.f,0.f,0.f};

    if (ta != tb) {
        #pragma unroll
        for (int cc = 0; cc < 16; ++cc) {
            const s8 av0 = *(const s8*)(A0 + cc * 512);
            const s8 av1 = *(const s8*)(A0 + GSTRIDE + cc * 512);
            const s8 bv0 = *(const s8*)(B0 + cc * 512);
            const s8 bv1 = *(const s8*)(B0 + GSTRIDE + cc * 512);
            acc00 = __builtin_amdgcn_mfma_f32_16x16x32_bf16(
                __builtin_bit_cast(bf8, av0), __builtin_bit_cast(bf8, bv0), acc00, 0, 0, 0);
            acc01 = __builtin_amdgcn_mfma_f32_16x16x32_bf16(
                __builtin_bit_cast(bf8, av0), __builtin_bit_cast(bf8, bv1), acc01, 0, 0, 0);
            acc10 = __builtin_amdgcn_mfma_f32_16x16x32_bf16(
                __builtin_bit_cast(bf8, av1), __builtin_bit_cast(bf8, bv0), acc10, 0, 0, 0);
            acc11 = __builtin_amdgcn_mfma_f32_16x16x32_bf16(
                __builtin_bit_cast(bf8, av1), __builtin_bit_cast(bf8, bv1), acc11, 0, 0, 0);
        }
    } else {
        #pragma unroll
        for (int cc = 0; cc < 16; ++cc) {
            const s8 av0 = *(const s8*)(A0 + cc * 512);
            const s8 av1 = *(const s8*)(A0 + GSTRIDE + cc * 512);
            acc00 = __builtin_amdgcn_mfma_f32_16x16x32_bf16(
                __builtin_bit_cast(bf8, av0), __builtin_bit_cast(bf8, av0), acc00, 0, 0, 0);
            acc01 = __builtin_amdgcn_mfma_f32_16x16x32_bf16(
                __builtin_bit_cast(bf8, av0), __builtin_bit_cast(bf8, av1), acc01, 0, 0, 0);
            acc10 = __builtin_amdgcn_mfma_f32_16x16x32_bf16(
                __builtin_bit_cast(bf8, av1), __builtin_bit_cast(bf8, av0), acc10, 0, 0, 0);
            acc11 = __builtin_amdgcn_mfma_f32_16x16x32_bf16(
                __builtin_bit_cast(bf8, av1), __builtin_bit_cast(bf8, av1), acc11, 0, 0, 0);
        }
    }

    float* gb = gp + ((size_t)blockIdx.y * NT32 + blockIdx.x) * 1024;
    #pragma unroll
    for (int r = 0; r < 4; ++r) {
        const int ar0 = (l4 * 4 + r) * 32 + l15;     // C/D: row=(l>>4)*4+r, col=l&15
        gb[ar0]           = acc00[r];
        gb[ar0 + 16]      = acc01[r];
        gb[ar0 + 16 * 32] = acc10[r];
        gb[ar0 + 16 * 33] = acc11[r];
    }
}

// --- K3: s2 += wgt*(sum_K gp)^2 over gp cells  AND  -2*s_a^2 over features;
//     last-ticket block writes loss = (N^2 + s2)/N^2. ---
__global__ __launch_bounds__(256) void k_reduce_final(
    const float* __restrict__ gp, const float* __restrict__ parts,
    float* __restrict__ s2, int* __restrict__ ticket, float* __restrict__ out)
{
    __shared__ float part[4], svp[4];
    __shared__ int lastFlag;
    const int t = threadIdx.x, lane = t & 63, wv = t >> 6;
    const int c = blockIdx.x * 256 + t;              // f4 cell, 34816 total
    const f4* g4 = (const f4*)gp;
    f4 s = {0.f, 0.f, 0.f, 0.f};
    #pragma unroll
    for (int p = 0; p < KOUT; ++p) s += g4[(size_t)p * (NT32 * 256) + c];
    int tt = c >> 8, ta = 0;                         // 256 f4 per tile plane
    while (tt >= 16 - ta) { tt -= 16 - ta; ++ta; }
    const float wgt = (tt == 0) ? 1.f : 2.f;         // diag vs off-diag tile
    float sq = wgt * (s.x * s.x + s.y * s.y + s.z * s.z + s.w * s.w);
    #pragma unroll
    for (int off = 1; off < 64; off <<= 1) sq += __shfl_xor(sq, off, 64);
    if (lane == 0) part[wv] = sq;

    // s1 slice: blocks 0..127, wave wv owns feature a = blk*4 + wv
    float sv = 0.f;
    if (blockIdx.x < 128) {
        const int a = blockIdx.x * 4 + wv;
        #pragma unroll
        for (int pb = 0; pb < 4; ++pb) sv += parts[(size_t)(pb * 64 + lane) * 512 + a];
        #pragma unroll
        for (int off = 1; off < 64; off <<= 1) sv += __shfl_xor(sv, off, 64);
    }
    if (lane == 0) svp[wv] = sv;
    __syncthreads();
    if (t == 0) {
        const float tot = part[0] + part[1] + part[2] + part[3]
            - 2.f * (svp[0]*svp[0] + svp[1]*svp[1] + svp[2]*svp[2] + svp[3]*svp[3]);
        atomicAdd(s2, tot);
        __threadfence();
        lastFlag = (atomicAdd(ticket, 1) == (int)gridDim.x - 1);
    }
    __syncthreads();
    if (lastFlag) {                                  // block-uniform
        __threadfence();
        if (t == 0) {
            const float S = atomicAdd(s2, 0.f);      // full S2 - 2*s1
            const double NN = 67108864.0;            // 8192^2
            out[0] = (float)((NN + (double)S) / NN);
        }
    }
}

extern "C" void kernel_launch(void* const* d_in, const int* in_sizes, int n_in,
                              void* d_out, int out_size, void* d_ws, size_t ws_size,
                              hipStream_t stream)
{
    const float* reps = (const float*)d_in[0];
    // d_in[1] (labels) is mathematically irrelevant for margin = 1.0.
    char* ws = (char*)d_ws;
    unsigned short* xt   = (unsigned short*)(ws + OFF_XT);
    float*          s2   = (float*)(ws + OFF_S2);
    int*            tick = (int*)(ws + OFF_TK);
    float*          prt  = (float*)(ws + OFF_PRT);
    float*          gp   = (float*)(ws + OFF_GP);

    k_prep<<<256, 256, 0, stream>>>(reps, xt, prt, s2, tick);
    k_gram<<<dim3(NT32, KOUT), 64, 0, stream>>>(xt, gp);
    k_reduce_final<<<NT32, 256, 0, stream>>>(gp, prt, s2, tick, (float*)d_out);
}